// Round 1
// baseline (186.337 us; speedup 1.0000x reference)
//
#include <hip/hip_runtime.h>
#include <hip/hip_bf16.h>
#include <math.h>

// ---------- types ----------
typedef __attribute__((ext_vector_type(8))) short s8v;   // 8 bf16 (4 VGPRs) - MFMA A/B frag
typedef __attribute__((ext_vector_type(4))) float f4v;   // 4 f32 - MFMA C/D frag
typedef __attribute__((ext_vector_type(4))) int   i4v;   // 16B vector load/store

#define HW   512
#define NIMG 24
#define MAT  (HW*HW)   // 262144

// round-to-nearest-even f32 -> bf16 bits
__device__ __forceinline__ unsigned short f2bf(float f) {
  unsigned u = __builtin_bit_cast(unsigned, f);
  u += 0x7fffu + ((u >> 16) & 1u);
  return (unsigned short)(u >> 16);
}

__device__ __forceinline__ int band_of(int s) {
  return s == 0 ? 30 : (s == 1 ? 160 : 500);
}

// ---------- G matrix generation: G[s][i][j] = g_s(j-i), bf16 ----------
__global__ void ggen_kernel(unsigned short* __restrict__ G,
                            float i2s0, float i2s1, float i2s2,
                            float n0, float n1, float n2) {
  int gid = blockIdx.x * 256 + threadIdx.x;
  if (gid >= 3 * MAT) return;
  int s   = gid >> 18;
  int rem = gid & (MAT - 1);
  int i = rem >> 9, j = rem & 511;
  int d = j - i;
  int ad = d < 0 ? -d : d;
  float i2s = (s == 0) ? i2s0 : (s == 1 ? i2s1 : i2s2);
  float nrm = (s == 0) ? n0  : (s == 1 ? n1  : n2);
  float val = 0.f;
  if (ad <= band_of(s)) val = expf(-(float)(d * d) * i2s) * nrm;
  G[gid] = f2bf(val);
}

// ---------- out = log1p(x) ----------
__global__ void init_out_kernel(const float* __restrict__ x, float* __restrict__ out, int n) {
  int i = blockIdx.x * 256 + threadIdx.x;
  if (i < n) out[i] = log1pf(x[i]);
}

// ---------- shared MFMA compute for one BK=64 K-step ----------
__device__ __forceinline__ void compute_bk(const short* As, const short* Bs,
                                           int wr, int wc, int lrow, int lq,
                                           f4v (&acc)[4][4]) {
  #pragma unroll
  for (int kk = 0; kk < 2; ++kk) {
    s8v af[4], bf[4];
    int ko = kk * 32 + lq * 8;
    #pragma unroll
    for (int mi = 0; mi < 4; ++mi)
      af[mi] = *(const s8v*)&As[(wr + mi * 16 + lrow) * 64 + ko];
    #pragma unroll
    for (int ni = 0; ni < 4; ++ni)
      bf[ni] = *(const s8v*)&Bs[(wc + ni * 16 + lrow) * 64 + ko];
    #pragma unroll
    for (int mi = 0; mi < 4; ++mi)
      #pragma unroll
      for (int ni = 0; ni < 4; ++ni)
        acc[mi][ni] = __builtin_amdgcn_mfma_f32_16x16x32_bf16(af[mi], bf[ni], acc[mi][ni], 0, 0, 0);
  }
}

// ---------- pass 1: Ut[s][img][w][h'] = sum_{w'} X[img][h'][w'] * G_s[w][w'] ----------
// GEMM: A = G_s (M=w, K=w'), Bt = X[img] (N=h', K=w'), D[m][n] stored at Ut[m][n].
__global__ __launch_bounds__(256) void pass1_kernel(
    const float* __restrict__ X,
    const unsigned short* __restrict__ G,
    unsigned short* __restrict__ Ut,
    int scale0) {
  __shared__ short As[128 * 64];
  __shared__ short Bs[128 * 64];

  int bid  = blockIdx.x;
  int sl   = bid / (NIMG * 16);
  int rem  = bid - sl * (NIMG * 16);
  int img  = rem >> 4;
  int tile = rem & 15;
  int m0 = (tile >> 2) * 128;
  int n0 = (tile & 3) * 128;
  int s  = scale0 + sl;
  int band = band_of(s);

  const unsigned short* A = G + s * MAT;
  const float* B = X + img * MAT;
  unsigned short* O = Ut + (sl * NIMG + img) * MAT;

  int t = threadIdx.x;
  int lane = t & 63;
  int wv = t >> 6;
  int wr = (wv >> 1) * 64;
  int wc = (wv & 1) * 64;
  int lrow = lane & 15;
  int lq   = lane >> 4;

  f4v acc[4][4];
  #pragma unroll
  for (int mi = 0; mi < 4; ++mi)
    #pragma unroll
    for (int ni = 0; ni < 4; ++ni)
      #pragma unroll
      for (int r = 0; r < 4; ++r) acc[mi][ni][r] = 0.f;

  int lo = m0 - band; if (lo < 0) lo = 0;
  int hi = m0 + 128 + band; if (hi > 512) hi = 512;
  int kb_lo = lo >> 6;
  int kb_hi = (hi + 63) >> 6;

  for (int kb = kb_lo; kb < kb_hi; ++kb) {
    int k0 = kb << 6;
    i4v ga[4];
    f4v gb[4][2];
    #pragma unroll
    for (int c = 0; c < 4; ++c) {
      int idx = c * 256 + t;
      int row = idx >> 3, k8 = (idx & 7) << 3;
      ga[c] = *(const i4v*)(A + (m0 + row) * HW + k0 + k8);
      const float* bp = B + (n0 + row) * HW + k0 + k8;
      gb[c][0] = *(const f4v*)bp;
      gb[c][1] = *(const f4v*)(bp + 4);
    }
    __syncthreads();   // previous iteration's LDS readers done
    #pragma unroll
    for (int c = 0; c < 4; ++c) {
      int idx = c * 256 + t;
      int row = idx >> 3, k8 = (idx & 7) << 3;
      *(i4v*)&As[(row << 6) + k8] = ga[c];
      s8v pb;
      #pragma unroll
      for (int e = 0; e < 4; ++e) {
        pb[e]     = (short)f2bf(gb[c][0][e]);
        pb[4 + e] = (short)f2bf(gb[c][1][e]);
      }
      *(s8v*)&Bs[(row << 6) + k8] = pb;
    }
    __syncthreads();
    compute_bk(As, Bs, wr, wc, lrow, lq, acc);
  }

  // store D[m][n] as bf16 (already in Ut layout)
  #pragma unroll
  for (int mi = 0; mi < 4; ++mi)
    #pragma unroll
    for (int r = 0; r < 4; ++r) {
      int m = m0 + wr + mi * 16 + lq * 4 + r;
      #pragma unroll
      for (int ni = 0; ni < 4; ++ni) {
        int n = n0 + wc + ni * 16 + lrow;
        O[m * HW + n] = f2bf(acc[mi][ni][r]);
      }
    }
}

// ---------- pass 2: Z[h][w] = sum_{h'} G_s[h][h'] * Ut[s][img][w][h']; out -= sum_s log1p(Z)/3 ----------
// GEMM: A = G_s (M=h, K=h'), Bt = Ut row-major (N=w, K=h'), D[m][n] = Z[h=m][w=n].
__global__ __launch_bounds__(256) void pass2_kernel(
    const unsigned short* __restrict__ G,
    const unsigned short* __restrict__ Ut,
    float* __restrict__ out,
    int scale0, int nscales) {
  __shared__ short As[128 * 64];
  __shared__ short Bs[128 * 64];

  int bid  = blockIdx.x;
  int img  = bid >> 4;
  int tile = bid & 15;
  int m0 = (tile >> 2) * 128;
  int n0 = (tile & 3) * 128;

  int t = threadIdx.x;
  int lane = t & 63;
  int wv = t >> 6;
  int wr = (wv >> 1) * 64;
  int wc = (wv & 1) * 64;
  int lrow = lane & 15;
  int lq   = lane >> 4;

  float suml[4][4][4];
  #pragma unroll
  for (int mi = 0; mi < 4; ++mi)
    #pragma unroll
    for (int ni = 0; ni < 4; ++ni)
      #pragma unroll
      for (int r = 0; r < 4; ++r) suml[mi][ni][r] = 0.f;

  for (int sl = 0; sl < nscales; ++sl) {
    int s = scale0 + sl;
    int band = band_of(s);
    const unsigned short* A = G + s * MAT;
    const unsigned short* B = Ut + (sl * NIMG + img) * MAT;

    f4v acc[4][4];
    #pragma unroll
    for (int mi = 0; mi < 4; ++mi)
      #pragma unroll
      for (int ni = 0; ni < 4; ++ni)
        #pragma unroll
        for (int r = 0; r < 4; ++r) acc[mi][ni][r] = 0.f;

    int lo = m0 - band; if (lo < 0) lo = 0;
    int hi = m0 + 128 + band; if (hi > 512) hi = 512;
    int kb_lo = lo >> 6;
    int kb_hi = (hi + 63) >> 6;

    for (int kb = kb_lo; kb < kb_hi; ++kb) {
      int k0 = kb << 6;
      i4v ga[4], gbv[4];
      #pragma unroll
      for (int c = 0; c < 4; ++c) {
        int idx = c * 256 + t;
        int row = idx >> 3, k8 = (idx & 7) << 3;
        ga[c]  = *(const i4v*)(A + (m0 + row) * HW + k0 + k8);
        gbv[c] = *(const i4v*)(B + (n0 + row) * HW + k0 + k8);
      }
      __syncthreads();
      #pragma unroll
      for (int c = 0; c < 4; ++c) {
        int idx = c * 256 + t;
        int row = idx >> 3, k8 = (idx & 7) << 3;
        *(i4v*)&As[(row << 6) + k8] = ga[c];
        *(i4v*)&Bs[(row << 6) + k8] = gbv[c];
      }
      __syncthreads();
      compute_bk(As, Bs, wr, wc, lrow, lq, acc);
    }

    #pragma unroll
    for (int mi = 0; mi < 4; ++mi)
      #pragma unroll
      for (int ni = 0; ni < 4; ++ni)
        #pragma unroll
        for (int r = 0; r < 4; ++r)
          suml[mi][ni][r] += log1pf(acc[mi][ni][r]);
  }

  float* O = out + img * MAT;
  #pragma unroll
  for (int mi = 0; mi < 4; ++mi)
    #pragma unroll
    for (int r = 0; r < 4; ++r) {
      int m = m0 + wr + mi * 16 + lq * 4 + r;
      #pragma unroll
      for (int ni = 0; ni < 4; ++ni) {
        int n = n0 + wc + ni * 16 + lrow;
        float* p = O + m * HW + n;
        *p -= suml[mi][ni][r] * (1.0f / 3.0f);
      }
    }
}

// ---------- host ----------
extern "C" void kernel_launch(void* const* d_in, const int* in_sizes, int n_in,
                              void* d_out, int out_size, void* d_ws, size_t ws_size,
                              hipStream_t stream) {
  (void)in_sizes; (void)n_in; (void)out_size;
  const float* x = (const float*)d_in[0];
  float* out = (float*)d_out;
  unsigned short* Gbuf = (unsigned short*)d_ws;
  unsigned short* Ut   = Gbuf + 3 * MAT;

  static const int scales[3] = {15, 80, 250};
  float i2s[3], nrm[3];
  for (int si = 0; si < 3; ++si) {
    double s = (double)scales[si];
    double S = 0.0;
    for (int c = -2 * scales[si]; c <= 2 * scales[si]; ++c)
      S += exp(-(double)c * (double)c / (2.0 * s * s));
    i2s[si] = (float)(1.0 / (2.0 * s * s));
    nrm[si] = (float)(1.0 / S);
  }

  ggen_kernel<<<(3 * MAT + 255) / 256, 256, 0, stream>>>(
      Gbuf, i2s[0], i2s[1], i2s[2], nrm[0], nrm[1], nrm[2]);
  init_out_kernel<<<(NIMG * MAT + 255) / 256, 256, 0, stream>>>(x, out, NIMG * MAT);

  size_t need_batched = (size_t)(3 + 3 * NIMG) * MAT * 2;
  if (ws_size >= need_batched) {
    pass1_kernel<<<3 * NIMG * 16, 256, 0, stream>>>(x, Gbuf, Ut, 0);
    pass2_kernel<<<NIMG * 16, 256, 0, stream>>>(Gbuf, Ut, out, 0, 3);
  } else {
    for (int s = 0; s < 3; ++s) {
      pass1_kernel<<<NIMG * 16, 256, 0, stream>>>(x, Gbuf, Ut, s);
      pass2_kernel<<<NIMG * 16, 256, 0, stream>>>(Gbuf, Ut, out, s, 1);
    }
  }
}

// Round 2
// 126.364 us; speedup vs baseline: 1.4746x; 1.4746x over previous
//
#include <hip/hip_runtime.h>
#include <hip/hip_bf16.h>
#include <math.h>

// ---------- types ----------
typedef __attribute__((ext_vector_type(8))) short s8v;   // 8 bf16 (4 VGPRs) - MFMA A/B frag
typedef __attribute__((ext_vector_type(4))) short s4v;   // 4 bf16 (8B store)
typedef __attribute__((ext_vector_type(4))) float f4v;   // 4 f32 - MFMA C/D frag
typedef __attribute__((ext_vector_type(4))) int   i4v;   // 16B vector load/store

#define HW   512
#define NIMG 24
#define MAT  (HW*HW)   // 262144

// round-to-nearest-even f32 -> bf16 bits
__device__ __forceinline__ unsigned short f2bf(float f) {
  unsigned u = __builtin_bit_cast(unsigned, f);
  u += 0x7fffu + ((u >> 16) & 1u);
  return (unsigned short)(u >> 16);
}

__device__ __forceinline__ int band_of(int s) {
  return s == 0 ? 30 : (s == 1 ? 160 : 500);   // 2*scale
}

// ---------- G matrix generation: G[s][i][j] = g_s(j-i), bf16 ----------
__global__ void ggen_kernel(unsigned short* __restrict__ G,
                            float i2s0, float i2s1, float i2s2,
                            float n0, float n1, float n2) {
  int gid = blockIdx.x * 256 + threadIdx.x;
  if (gid >= 3 * MAT) return;
  int s   = gid >> 18;
  int rem = gid & (MAT - 1);
  int i = rem >> 9, j = rem & 511;
  int d = j - i;
  int ad = d < 0 ? -d : d;
  float i2s = (s == 0) ? i2s0 : (s == 1 ? i2s1 : i2s2);
  float nrm = (s == 0) ? n0  : (s == 1 ? n1  : n2);
  float val = 0.f;
  if (ad <= band_of(s)) val = expf(-(float)(d * d) * i2s) * nrm;
  G[gid] = f2bf(val);
}

// ---------- init: out = log1p(x); optionally Xb = bf16(x) ----------
__global__ __launch_bounds__(256) void init_kernel(
    const float* __restrict__ x, float* __restrict__ out,
    unsigned short* __restrict__ Xb, int writeXb) {
  int i = blockIdx.x * 256 + threadIdx.x;   // handles 4 elements
  f4v v = *(const f4v*)(x + (size_t)i * 4);
  f4v o;
  #pragma unroll
  for (int e = 0; e < 4; ++e) o[e] = log1pf(v[e]);
  *(f4v*)(out + (size_t)i * 4) = o;
  if (writeXb) {
    s4v b;
    #pragma unroll
    for (int e = 0; e < 4; ++e) b[e] = (short)f2bf(v[e]);
    *(s4v*)(Xb + (size_t)i * 4) = b;
  }
}

// ---------- swizzled LDS helpers ----------
// LDS tile: 128 rows x 64 bf16 (128B/row). 16B chunk `ch` of row r lives at
// byte r*128 + (ch ^ (r&7))*16  (T2 XOR swizzle; 2-way read conflict = free).
// global_load_lds writes LINEARLY (base + lane*16), so the *source* address
// is pre-permuted instead (rule #21: both-sides-or-neither).
__device__ __forceinline__ void stage_tile(const unsigned short* __restrict__ src,
                                           short* lds, int w, int l) {
  #pragma unroll
  for (int c = 0; c < 4; ++c) {
    int cid = ((c << 2) + w);              // 16 chunk-groups of 1KB
    int chunk = cid * 64 + l;              // 16B chunk id within 16KB tile
    int row = chunk >> 3, ch = chunk & 7;
    const char* g = (const char*)src + row * (HW * 2) + ((ch ^ (row & 7)) << 4);
    __builtin_amdgcn_global_load_lds(
        (const __attribute__((address_space(1))) void*)g,
        (__attribute__((address_space(3))) void*)(lds + (cid << 9)),
        16, 0, 0);
  }
}

__device__ __forceinline__ s8v lds_frag(const short* base, int row, int chunk) {
  return *(const s8v*)((const char*)base + row * 128 + ((chunk ^ (row & 7)) << 4));
}

// ---------- MFMA compute for one BK=64 K-step (swizzled reads) ----------
__device__ __forceinline__ void compute_bk(const short* As, const short* Bs,
                                           int wr, int wc, int lrow, int lq,
                                           f4v (&acc)[4][4]) {
  #pragma unroll
  for (int kk = 0; kk < 2; ++kk) {
    s8v af[4], bf[4];
    int chunk = (kk << 2) + lq;
    #pragma unroll
    for (int mi = 0; mi < 4; ++mi)
      af[mi] = lds_frag(As, wr + mi * 16 + lrow, chunk);
    #pragma unroll
    for (int ni = 0; ni < 4; ++ni)
      bf[ni] = lds_frag(Bs, wc + ni * 16 + lrow, chunk);
    #pragma unroll
    for (int mi = 0; mi < 4; ++mi)
      #pragma unroll
      for (int ni = 0; ni < 4; ++ni)
        acc[mi][ni] = __builtin_amdgcn_mfma_f32_16x16x32_bf16(af[mi], bf[ni], acc[mi][ni], 0, 0, 0);
  }
}

// ---------- unified banded bf16 GEMM ----------
// D[m][n] = sum_k A[m][k]*B[n][k],  A = G_s, B = Xb[img] (PASS 1) or Ut[sl][img] (PASS 2).
// PASS 1: Ut[sl][img][m][n] = bf16(D).   PASS 2: out[img][m][n] += -log1p(D)/3 (atomic).
template<int PASS>
__global__ __launch_bounds__(256) void gemm_kernel(
    const unsigned short* __restrict__ G,
    const unsigned short* __restrict__ Bmat,
    unsigned short* __restrict__ Ut,
    float* __restrict__ out,
    int scale0) {
  __shared__ short As[128 * 64];
  __shared__ short Bs[128 * 64];

  int bid  = blockIdx.x;
  int tile = bid & 15;
  int img  = (bid >> 4) % NIMG;
  int sl   = (bid >> 4) / NIMG;
  int s    = scale0 + sl;
  int band = band_of(s);
  int m0 = (tile >> 2) * 128;
  int n0 = (tile & 3) * 128;

  const unsigned short* A = G + s * MAT + m0 * HW;
  const unsigned short* B = (PASS == 1 ? Bmat + img * MAT
                                       : Bmat + (sl * NIMG + img) * MAT) + n0 * HW;

  int t = threadIdx.x;
  int lane = t & 63;
  int w  = t >> 6;
  int wr = (w >> 1) * 64;
  int wc = (w & 1) * 64;
  int lrow = lane & 15;
  int lq   = lane >> 4;

  f4v acc[4][4];
  #pragma unroll
  for (int mi = 0; mi < 4; ++mi)
    #pragma unroll
    for (int ni = 0; ni < 4; ++ni)
      #pragma unroll
      for (int r = 0; r < 4; ++r) acc[mi][ni][r] = 0.f;

  int lo = m0 - band; if (lo < 0) lo = 0;
  int hi = m0 + 128 + band; if (hi > HW) hi = HW;
  int kb_lo = lo >> 6;
  int kb_hi = (hi + 63) >> 6;

  for (int kb = kb_lo; kb < kb_hi; ++kb) {
    int k0 = kb << 6;
    __syncthreads();                    // previous iteration's LDS readers done
    stage_tile(A + k0, As, w, lane);
    stage_tile(B + k0, Bs, w, lane);
    __syncthreads();                    // compiler drains vmcnt(0) before barrier
    compute_bk(As, Bs, wr, wc, lrow, lq, acc);
  }

  if (PASS == 1) {
    unsigned short* O = Ut + (sl * NIMG + img) * MAT;
    #pragma unroll
    for (int mi = 0; mi < 4; ++mi)
      #pragma unroll
      for (int r = 0; r < 4; ++r) {
        int m = m0 + wr + mi * 16 + lq * 4 + r;
        #pragma unroll
        for (int ni = 0; ni < 4; ++ni) {
          int n = n0 + wc + ni * 16 + lrow;
          O[m * HW + n] = f2bf(acc[mi][ni][r]);
        }
      }
  } else {
    float* O = out + img * MAT;
    #pragma unroll
    for (int mi = 0; mi < 4; ++mi)
      #pragma unroll
      for (int r = 0; r < 4; ++r) {
        int m = m0 + wr + mi * 16 + lq * 4 + r;
        #pragma unroll
        for (int ni = 0; ni < 4; ++ni) {
          int n = n0 + wc + ni * 16 + lrow;
          atomicAdd(O + m * HW + n, log1pf(acc[mi][ni][r]) * (-1.0f / 3.0f));
        }
      }
  }
}

// ---------- fallback pass1 (reg-staged fp32 -> bf16), swizzled LDS writes ----------
__global__ __launch_bounds__(256) void pass1_fb_kernel(
    const float* __restrict__ X,
    const unsigned short* __restrict__ G,
    unsigned short* __restrict__ Ut,
    int s) {
  __shared__ short As[128 * 64];
  __shared__ short Bs[128 * 64];

  int bid  = blockIdx.x;
  int img  = bid >> 4;
  int tile = bid & 15;
  int m0 = (tile >> 2) * 128;
  int n0 = (tile & 3) * 128;
  int band = band_of(s);

  const unsigned short* A = G + s * MAT;
  const float* B = X + img * MAT;
  unsigned short* O = Ut + img * MAT;

  int t = threadIdx.x;
  int lane = t & 63;
  int w = t >> 6;
  int wr = (w >> 1) * 64;
  int wc = (w & 1) * 64;
  int lrow = lane & 15;
  int lq   = lane >> 4;

  f4v acc[4][4];
  #pragma unroll
  for (int mi = 0; mi < 4; ++mi)
    #pragma unroll
    for (int ni = 0; ni < 4; ++ni)
      #pragma unroll
      for (int r = 0; r < 4; ++r) acc[mi][ni][r] = 0.f;

  int lo = m0 - band; if (lo < 0) lo = 0;
  int hi = m0 + 128 + band; if (hi > HW) hi = HW;
  int kb_lo = lo >> 6;
  int kb_hi = (hi + 63) >> 6;

  for (int kb = kb_lo; kb < kb_hi; ++kb) {
    int k0 = kb << 6;
    i4v ga[4];
    f4v gb[4][2];
    #pragma unroll
    for (int c = 0; c < 4; ++c) {
      int idx = c * 256 + t;
      int row = idx >> 3, k8 = (idx & 7) << 3;
      ga[c] = *(const i4v*)(A + (m0 + row) * HW + k0 + k8);
      const float* bp = B + (n0 + row) * HW + k0 + k8;
      gb[c][0] = *(const f4v*)bp;
      gb[c][1] = *(const f4v*)(bp + 4);
    }
    __syncthreads();
    #pragma unroll
    for (int c = 0; c < 4; ++c) {
      int idx = c * 256 + t;
      int row = idx >> 3, k8i = idx & 7;
      int soff = (row << 6) + (((k8i) ^ (row & 7)) << 3);   // swizzled
      *(i4v*)&As[soff] = ga[c];
      s8v pb;
      #pragma unroll
      for (int e = 0; e < 4; ++e) {
        pb[e]     = (short)f2bf(gb[c][0][e]);
        pb[4 + e] = (short)f2bf(gb[c][1][e]);
      }
      *(s8v*)&Bs[soff] = pb;
    }
    __syncthreads();
    compute_bk(As, Bs, wr, wc, lrow, lq, acc);
  }

  #pragma unroll
  for (int mi = 0; mi < 4; ++mi)
    #pragma unroll
    for (int r = 0; r < 4; ++r) {
      int m = m0 + wr + mi * 16 + lq * 4 + r;
      #pragma unroll
      for (int ni = 0; ni < 4; ++ni) {
        int n = n0 + wc + ni * 16 + lrow;
        O[m * HW + n] = f2bf(acc[mi][ni][r]);
      }
    }
}

// ---------- host ----------
extern "C" void kernel_launch(void* const* d_in, const int* in_sizes, int n_in,
                              void* d_out, int out_size, void* d_ws, size_t ws_size,
                              hipStream_t stream) {
  (void)in_sizes; (void)n_in; (void)out_size;
  const float* x = (const float*)d_in[0];
  float* out = (float*)d_out;
  unsigned short* Gbuf = (unsigned short*)d_ws;

  static const int scales[3] = {15, 80, 250};
  float i2s[3], nrm[3];
  for (int si = 0; si < 3; ++si) {
    double s = (double)scales[si];
    double S = 0.0;
    for (int c = -2 * scales[si]; c <= 2 * scales[si]; ++c)
      S += exp(-(double)c * (double)c / (2.0 * s * s));
    i2s[si] = (float)(1.0 / (2.0 * s * s));
    nrm[si] = (float)(1.0 / S);
  }

  ggen_kernel<<<(3 * MAT + 255) / 256, 256, 0, stream>>>(
      Gbuf, i2s[0], i2s[1], i2s[2], nrm[0], nrm[1], nrm[2]);

  size_t need_main = (size_t)(3 + 3 * NIMG + NIMG) * MAT * 2;  // G + Ut(3) + Xb
  if (ws_size >= need_main) {
    unsigned short* Ut = Gbuf + 3 * MAT;
    unsigned short* Xb = Ut + 3 * NIMG * MAT;
    init_kernel<<<NIMG * MAT / 1024, 256, 0, stream>>>(x, out, Xb, 1);
    gemm_kernel<1><<<3 * NIMG * 16, 256, 0, stream>>>(Gbuf, Xb, Ut, out, 0);
    gemm_kernel<2><<<3 * NIMG * 16, 256, 0, stream>>>(Gbuf, Ut, Ut, out, 0);
  } else {
    unsigned short* Ut = Gbuf + 3 * MAT;   // per-scale, NIMG*MAT
    init_kernel<<<NIMG * MAT / 1024, 256, 0, stream>>>(x, out, Ut, 0);
    for (int s = 0; s < 3; ++s) {
      pass1_fb_kernel<<<NIMG * 16, 256, 0, stream>>>(x, Gbuf, Ut, s);
      gemm_kernel<2><<<NIMG * 16, 256, 0, stream>>>(Gbuf, Ut, Ut, out, s);
    }
  }
}

// Round 3
// 61.019 us; speedup vs baseline: 3.0538x; 2.0709x over previous
//
#include <hip/hip_runtime.h>
#include <hip/hip_bf16.h>
#include <math.h>

// ---------- types ----------
typedef __attribute__((ext_vector_type(8))) short s8v;   // 8 bf16 (4 VGPRs) - MFMA A/B frag
typedef __attribute__((ext_vector_type(4))) short s4v;   // 4 bf16 (8B store)
typedef __attribute__((ext_vector_type(4))) float f4v;   // 4 f32 - MFMA C/D frag
typedef __attribute__((ext_vector_type(4))) int   i4v;   // 16B vector load/store

#define HW   512
#define NIMG 24
#define MAT  (HW*HW)   // 262144

// round-to-nearest-even f32 -> bf16 bits
__device__ __forceinline__ unsigned short f2bf(float f) {
  unsigned u = __builtin_bit_cast(unsigned, f);
  u += 0x7fffu + ((u >> 16) & 1u);
  return (unsigned short)(u >> 16);
}

__device__ __forceinline__ int band_of(int s) {
  return s == 0 ? 30 : (s == 1 ? 160 : 500);   // 2*scale
}

// fast log1p for z >= 0 (1+z exact in f32 up to rounding): v_log_f32 is log2, ~1 ulp
__device__ __forceinline__ float fast_log1p(float z) {
  float a = 1.0f + z;
  float l;
#if __has_builtin(__builtin_amdgcn_logf)
  l = __builtin_amdgcn_logf(a);
#else
  asm("v_log_f32 %0, %1" : "=v"(l) : "v"(a));
#endif
  return l * 0.69314718055994531f;
}

// ---------- prep: blocks [0,768) generate G (bf16); blocks [768, 768+6144) convert x->Xb
// (and optionally out = log1p(x) for the fallback path) ----------
#define NG_BLOCKS 768            // 3*MAT / (256*4)
#define NX_BLOCKS 6144           // NIMG*MAT / (256*4)
__global__ __launch_bounds__(256) void prep_kernel(
    const float* __restrict__ x,
    unsigned short* __restrict__ G,
    unsigned short* __restrict__ Xb,
    float* __restrict__ out, int writeOut,
    float i2s0, float i2s1, float i2s2,
    float n0, float n1, float n2) {
  int b = blockIdx.x;
  if (b < NG_BLOCKS) {
    int gid = b * 256 + threadIdx.x;     // one per 4 consecutive j
    int s   = gid >> 16;                 // 65536 quads per scale
    int rem = gid & 65535;
    int i = rem >> 7, j0 = (rem & 127) << 2;
    float i2s = (s == 0) ? i2s0 : (s == 1 ? i2s1 : i2s2);
    float nrm = (s == 0) ? n0  : (s == 1 ? n1  : n2);
    int band = band_of(s);
    s4v o;
    #pragma unroll
    for (int e = 0; e < 4; ++e) {
      int d = j0 + e - i;
      int ad = d < 0 ? -d : d;
      float val = 0.f;
      if (ad <= band) val = expf(-(float)(d * d) * i2s) * nrm;
      o[e] = (short)f2bf(val);
    }
    *(s4v*)(G + (size_t)gid * 4) = o;
  } else {
    int i = (b - NG_BLOCKS) * 256 + threadIdx.x;   // 4 elements each
    f4v v = *(const f4v*)(x + (size_t)i * 4);
    s4v bv;
    #pragma unroll
    for (int e = 0; e < 4; ++e) bv[e] = (short)f2bf(v[e]);
    *(s4v*)(Xb + (size_t)i * 4) = bv;
    if (writeOut) {
      f4v o;
      #pragma unroll
      for (int e = 0; e < 4; ++e) o[e] = fast_log1p(v[e]);
      *(f4v*)(out + (size_t)i * 4) = o;
    }
  }
}

// ---------- swizzled LDS helpers ----------
// LDS tile: NROWS x 64 bf16 (128B/row). 16B chunk `ch` of row r lives at
// byte r*128 + (ch ^ (r&7))*16. global_load_lds writes LINEARLY, so the
// *source* address is pre-permuted instead (both-sides-or-neither).
template<int NROWS>
__device__ __forceinline__ void stage_tile(const unsigned short* __restrict__ src,
                                           short* lds, int w, int l) {
  #pragma unroll
  for (int c = 0; c < NROWS / 32; ++c) {
    int cid = c * 4 + w;                   // 1KB chunk-groups
    int chunk = cid * 64 + l;              // 16B chunk id within tile
    int row = chunk >> 3, ch = chunk & 7;
    const char* g = (const char*)src + row * (HW * 2) + ((ch ^ (row & 7)) << 4);
    __builtin_amdgcn_global_load_lds(
        (const __attribute__((address_space(1))) void*)g,
        (__attribute__((address_space(3))) void*)(lds + (cid << 9)),
        16, 0, 0);
  }
}

__device__ __forceinline__ s8v lds_frag(const short* base, int row, int chunk) {
  return *(const s8v*)((const char*)base + row * 128 + ((chunk ^ (row & 7)) << 4));
}

// ---------- pass 1: Ut[sl][img][m][n] = bf16( sum_k G_s[m][k] * Xb[img][n][k] ) ----------
// BM=BN=128, grid = 3*NIMG*16 (proven structure, unchanged)
__global__ __launch_bounds__(256) void pass1_kernel(
    const unsigned short* __restrict__ G,
    const unsigned short* __restrict__ Xb,
    unsigned short* __restrict__ Ut) {
  __shared__ short As[128 * 64];
  __shared__ short Bs[128 * 64];

  int bid  = blockIdx.x;
  int tile = bid & 15;
  int img  = (bid >> 4) % NIMG;
  int sl   = (bid >> 4) / NIMG;
  int band = band_of(sl);
  int m0 = (tile >> 2) * 128;
  int n0 = (tile & 3) * 128;

  const unsigned short* A = G + sl * MAT + m0 * HW;
  const unsigned short* B = Xb + img * MAT + n0 * HW;

  int t = threadIdx.x;
  int lane = t & 63;
  int w  = t >> 6;
  int wr = (w >> 1) * 64;
  int wc = (w & 1) * 64;
  int lrow = lane & 15;
  int lq   = lane >> 4;

  f4v acc[4][4];
  #pragma unroll
  for (int mi = 0; mi < 4; ++mi)
    #pragma unroll
    for (int ni = 0; ni < 4; ++ni)
      #pragma unroll
      for (int r = 0; r < 4; ++r) acc[mi][ni][r] = 0.f;

  int lo = m0 - band; if (lo < 0) lo = 0;
  int hi = m0 + 128 + band; if (hi > HW) hi = HW;
  int kb_lo = lo >> 6;
  int kb_hi = (hi + 63) >> 6;

  for (int kb = kb_lo; kb < kb_hi; ++kb) {
    int k0 = kb << 6;
    __syncthreads();
    stage_tile<128>(A + k0, As, w, lane);
    stage_tile<128>(B + k0, Bs, w, lane);
    __syncthreads();
    #pragma unroll
    for (int kk = 0; kk < 2; ++kk) {
      s8v af[4], bf[4];
      int chunk = (kk << 2) + lq;
      #pragma unroll
      for (int mi = 0; mi < 4; ++mi)
        af[mi] = lds_frag(As, wr + mi * 16 + lrow, chunk);
      #pragma unroll
      for (int ni = 0; ni < 4; ++ni)
        bf[ni] = lds_frag(Bs, wc + ni * 16 + lrow, chunk);
      #pragma unroll
      for (int mi = 0; mi < 4; ++mi)
        #pragma unroll
        for (int ni = 0; ni < 4; ++ni)
          acc[mi][ni] = __builtin_amdgcn_mfma_f32_16x16x32_bf16(af[mi], bf[ni], acc[mi][ni], 0, 0, 0);
    }
  }

  unsigned short* O = Ut + (sl * NIMG + img) * MAT;
  #pragma unroll
  for (int mi = 0; mi < 4; ++mi)
    #pragma unroll
    for (int r = 0; r < 4; ++r) {
      int m = m0 + wr + mi * 16 + lq * 4 + r;
      #pragma unroll
      for (int ni = 0; ni < 4; ++ni) {
        int n = n0 + wc + ni * 16 + lrow;
        O[m * HW + n] = f2bf(acc[mi][ni][r]);
      }
    }
}

// ---------- pass 2 (fused over NS scales, NO atomics) ----------
// BM=128, BN=64; grid = NIMG*4*8 = 768; block owns out tile [m0:m0+128)x[n0:n0+64).
// Z_s[m][n] = sum_k G_s[m][k] * Ut[sl][img][n][k];  suml = sum_s log1p(Z_s)
// ACCUM=0: out = log1p(x) - suml/3   (plain store; covers every element once)
// ACCUM=1: out -= suml/3             (owner-block read-modify-write, no atomics)
template<int NS, int ACCUM>
__global__ __launch_bounds__(256) void pass2_kernel(
    const unsigned short* __restrict__ G,
    const unsigned short* __restrict__ Ut,
    const float* __restrict__ x,
    float* __restrict__ out,
    int scale0) {
  __shared__ short As[128 * 64];
  __shared__ short Bs[64 * 64];

  int bid  = blockIdx.x;
  int tile = bid & 31;            // 4 m-tiles x 8 n-tiles
  int img  = bid >> 5;
  int m0 = (tile >> 3) * 128;
  int n0 = (tile & 7) * 64;

  int t = threadIdx.x;
  int lane = t & 63;
  int w  = t >> 6;
  int wr = (w >> 1) * 64;         // wave rows {0,64}
  int wc = (w & 1) * 32;          // wave cols {0,32}
  int lrow = lane & 15;
  int lq   = lane >> 4;

  float suml[4][2][4];
  #pragma unroll
  for (int mi = 0; mi < 4; ++mi)
    #pragma unroll
    for (int ni = 0; ni < 2; ++ni)
      #pragma unroll
      for (int r = 0; r < 4; ++r) suml[mi][ni][r] = 0.f;

  for (int sl = 0; sl < NS; ++sl) {
    int s = scale0 + sl;
    int band = band_of(s);
    const unsigned short* A = G + s * MAT + m0 * HW;
    const unsigned short* B = Ut + (sl * NIMG + img) * MAT + n0 * HW;

    f4v acc[4][2];
    #pragma unroll
    for (int mi = 0; mi < 4; ++mi)
      #pragma unroll
      for (int ni = 0; ni < 2; ++ni)
        #pragma unroll
        for (int r = 0; r < 4; ++r) acc[mi][ni][r] = 0.f;

    int lo = m0 - band; if (lo < 0) lo = 0;
    int hi = m0 + 128 + band; if (hi > HW) hi = HW;
    int kb_lo = lo >> 6;
    int kb_hi = (hi + 63) >> 6;

    for (int kb = kb_lo; kb < kb_hi; ++kb) {
      int k0 = kb << 6;
      __syncthreads();
      stage_tile<128>(A + k0, As, w, lane);
      stage_tile<64>(B + k0, Bs, w, lane);
      __syncthreads();
      #pragma unroll
      for (int kk = 0; kk < 2; ++kk) {
        s8v af[4], bf[2];
        int chunk = (kk << 2) + lq;
        #pragma unroll
        for (int mi = 0; mi < 4; ++mi)
          af[mi] = lds_frag(As, wr + mi * 16 + lrow, chunk);
        #pragma unroll
        for (int ni = 0; ni < 2; ++ni)
          bf[ni] = lds_frag(Bs, wc + ni * 16 + lrow, chunk);
        #pragma unroll
        for (int mi = 0; mi < 4; ++mi)
          #pragma unroll
          for (int ni = 0; ni < 2; ++ni)
            acc[mi][ni] = __builtin_amdgcn_mfma_f32_16x16x32_bf16(af[mi], bf[ni], acc[mi][ni], 0, 0, 0);
      }
    }

    #pragma unroll
    for (int mi = 0; mi < 4; ++mi)
      #pragma unroll
      for (int ni = 0; ni < 2; ++ni)
        #pragma unroll
        for (int r = 0; r < 4; ++r)
          suml[mi][ni][r] += fast_log1p(acc[mi][ni][r]);
  }

  const float* xr = x + img * MAT;
  float* O = out + img * MAT;
  #pragma unroll
  for (int mi = 0; mi < 4; ++mi)
    #pragma unroll
    for (int r = 0; r < 4; ++r) {
      int m = m0 + wr + mi * 16 + lq * 4 + r;
      #pragma unroll
      for (int ni = 0; ni < 2; ++ni) {
        int n = n0 + wc + ni * 16 + lrow;
        int idx = m * HW + n;
        if (ACCUM) {
          O[idx] = O[idx] - suml[mi][ni][r] * (1.0f / 3.0f);
        } else {
          O[idx] = fast_log1p(xr[idx]) - suml[mi][ni][r] * (1.0f / 3.0f);
        }
      }
    }
}

// ---------- fallback pass1 (reg-staged fp32 -> bf16), swizzled LDS writes ----------
__global__ __launch_bounds__(256) void pass1_fb_kernel(
    const float* __restrict__ X,
    const unsigned short* __restrict__ G,
    unsigned short* __restrict__ Ut,
    int s) {
  __shared__ short As[128 * 64];
  __shared__ short Bs[128 * 64];

  int bid  = blockIdx.x;
  int img  = bid >> 4;
  int tile = bid & 15;
  int m0 = (tile >> 2) * 128;
  int n0 = (tile & 3) * 128;
  int band = band_of(s);

  const unsigned short* A = G + s * MAT;
  const float* B = X + img * MAT;
  unsigned short* O = Ut + img * MAT;

  int t = threadIdx.x;
  int lane = t & 63;
  int w = t >> 6;
  int wr = (w >> 1) * 64;
  int wc = (w & 1) * 64;
  int lrow = lane & 15;
  int lq   = lane >> 4;

  f4v acc[4][4];
  #pragma unroll
  for (int mi = 0; mi < 4; ++mi)
    #pragma unroll
    for (int ni = 0; ni < 4; ++ni)
      #pragma unroll
      for (int r = 0; r < 4; ++r) acc[mi][ni][r] = 0.f;

  int lo = m0 - band; if (lo < 0) lo = 0;
  int hi = m0 + 128 + band; if (hi > HW) hi = HW;
  int kb_lo = lo >> 6;
  int kb_hi = (hi + 63) >> 6;

  for (int kb = kb_lo; kb < kb_hi; ++kb) {
    int k0 = kb << 6;
    i4v ga[4];
    f4v gb[4][2];
    #pragma unroll
    for (int c = 0; c < 4; ++c) {
      int idx = c * 256 + t;
      int row = idx >> 3, k8 = (idx & 7) << 3;
      ga[c] = *(const i4v*)(A + (m0 + row) * HW + k0 + k8);
      const float* bp = B + (n0 + row) * HW + k0 + k8;
      gb[c][0] = *(const f4v*)bp;
      gb[c][1] = *(const f4v*)(bp + 4);
    }
    __syncthreads();
    #pragma unroll
    for (int c = 0; c < 4; ++c) {
      int idx = c * 256 + t;
      int row = idx >> 3, k8i = idx & 7;
      int soff = (row << 6) + ((k8i ^ (row & 7)) << 3);   // swizzled (short units)
      *(i4v*)&As[soff] = ga[c];
      s8v pb;
      #pragma unroll
      for (int e = 0; e < 4; ++e) {
        pb[e]     = (short)f2bf(gb[c][0][e]);
        pb[4 + e] = (short)f2bf(gb[c][1][e]);
      }
      *(s8v*)&Bs[soff] = pb;
    }
    __syncthreads();
    #pragma unroll
    for (int kk = 0; kk < 2; ++kk) {
      s8v af[4], bf[4];
      int chunk = (kk << 2) + lq;
      #pragma unroll
      for (int mi = 0; mi < 4; ++mi)
        af[mi] = lds_frag(As, wr + mi * 16 + lrow, chunk);
      #pragma unroll
      for (int ni = 0; ni < 4; ++ni)
        bf[ni] = lds_frag(Bs, wc + ni * 16 + lrow, chunk);
      #pragma unroll
      for (int mi = 0; mi < 4; ++mi)
        #pragma unroll
        for (int ni = 0; ni < 4; ++ni)
          acc[mi][ni] = __builtin_amdgcn_mfma_f32_16x16x32_bf16(af[mi], bf[ni], acc[mi][ni], 0, 0, 0);
    }
  }

  #pragma unroll
  for (int mi = 0; mi < 4; ++mi)
    #pragma unroll
    for (int r = 0; r < 4; ++r) {
      int m = m0 + wr + mi * 16 + lq * 4 + r;
      #pragma unroll
      for (int ni = 0; ni < 4; ++ni) {
        int n = n0 + wc + ni * 16 + lrow;
        O[m * HW + n] = f2bf(acc[mi][ni][r]);
      }
    }
}

// ---------- host ----------
extern "C" void kernel_launch(void* const* d_in, const int* in_sizes, int n_in,
                              void* d_out, int out_size, void* d_ws, size_t ws_size,
                              hipStream_t stream) {
  (void)in_sizes; (void)n_in; (void)out_size;
  const float* x = (const float*)d_in[0];
  float* out = (float*)d_out;
  unsigned short* Gbuf = (unsigned short*)d_ws;

  static const int scales[3] = {15, 80, 250};
  float i2s[3], nrm[3];
  for (int si = 0; si < 3; ++si) {
    double s = (double)scales[si];
    double S = 0.0;
    for (int c = -2 * scales[si]; c <= 2 * scales[si]; ++c)
      S += exp(-(double)c * (double)c / (2.0 * s * s));
    i2s[si] = (float)(1.0 / (2.0 * s * s));
    nrm[si] = (float)(1.0 / S);
  }

  size_t need_main = (size_t)(3 + 3 * NIMG + NIMG) * MAT * 2;  // G + Ut(3) + Xb
  if (ws_size >= need_main) {
    unsigned short* Ut = Gbuf + 3 * MAT;
    unsigned short* Xb = Ut + (size_t)3 * NIMG * MAT;
    prep_kernel<<<NG_BLOCKS + NX_BLOCKS, 256, 0, stream>>>(
        x, Gbuf, Xb, out, 0, i2s[0], i2s[1], i2s[2], nrm[0], nrm[1], nrm[2]);
    pass1_kernel<<<3 * NIMG * 16, 256, 0, stream>>>(Gbuf, Xb, Ut);
    pass2_kernel<3, 0><<<NIMG * 32, 256, 0, stream>>>(Gbuf, Ut, x, out, 0);
  } else {
    unsigned short* Ut = Gbuf + 3 * MAT;   // per-scale, NIMG*MAT
    unsigned short* Xb = Ut;               // unused sink (fallback stages from f32 x)
    prep_kernel<<<NG_BLOCKS + NX_BLOCKS, 256, 0, stream>>>(
        x, Gbuf, Xb, out, 1, i2s[0], i2s[1], i2s[2], nrm[0], nrm[1], nrm[2]);
    for (int s = 0; s < 3; ++s) {
      pass1_fb_kernel<<<NIMG * 16, 256, 0, stream>>>(x, Gbuf, Ut, s);
      pass2_kernel<1, 1><<<NIMG * 32, 256, 0, stream>>>(Gbuf, Ut, x, out, s);
    }
  }
}